// Round 12
// baseline (436.503 us; speedup 1.0000x reference)
//
#include <hip/hip_runtime.h>
#include <cmath>

typedef unsigned short u16;
typedef unsigned char u8;
typedef unsigned int u32;
typedef short bf16x8 __attribute__((ext_vector_type(8)));
typedef float f32x4 __attribute__((ext_vector_type(4)));
typedef float f32x2 __attribute__((ext_vector_type(2)));

#define NN 50000      // nodes
#define MP 50048      // padded to 128*391
#define EE 400000     // raw edges
#define ET 450000     // edges + self loops
#define HIDD 256
#define KIN 192       // 3*F
#define LN_EPSF 1e-5f

__device__ __forceinline__ float bf2f(u16 u){ return __uint_as_float(((u32)u)<<16); }
__device__ __forceinline__ u16 f2bf(float f){
  u32 x = __float_as_uint(f);
  u32 r = x + 0x7fffu + ((x>>16)&1u);   // RNE
  return (u16)(r>>16);
}
__device__ __forceinline__ u32 pack2(float a, float b){ return (u32)f2bf(a) | ((u32)f2bf(b)<<16); }
__device__ __forceinline__ u8 f2fp8(float v){
  return (u8)(__builtin_amdgcn_cvt_pk_fp8_f32(v, v, 0, false) & 0xff);  // OCP e4m3, RNE+sat
}

__device__ __forceinline__ void dma16(const u16* g, u16* lds){
  __builtin_amdgcn_global_load_lds(
      (const __attribute__((address_space(1))) void*)g,
      (__attribute__((address_space(3))) void*)lds, 16, 0, 0);
}

// ================ merged setup ================
// Inproj GEMM is algebraically fused into layer 0:
//   h0 = feats@(Win@W0) + b_in@W0 ; scores0 = feats@(Win·(W0·a)) + (b_in@W0)·a
// Block partition:
//   [0,1564)     A1: feats x-part      (MP*8 vec8 units)
//   [1564,3128)  A2: feats remb-part
//   [3128,4692)  A3: feats posenc-part
//   [4692,5908)  B : wtin = (Win@W0)^T (fused, 256-dot each) | wtl transposes
//   [5908,5972)  C : vmat (layers; l=0 slot unused)
//   [5972,5980)  F : vmatc[16][192] = Win·(W0·a) fused score mat (8 blocks)
//   [5980,5981)  G : bias0[256] = b_in@W0 ; bias0[256..264) = score consts
//   [5981,7739)  D : degree atomics    (ET elems)
__global__ __launch_bounds__(256) void k_setup(
    const float* __restrict__ x, const float* __restrict__ remb, const int* __restrict__ rid,
    u16* __restrict__ feats,
    const float* __restrict__ ipw, const float* __restrict__ gatw,
    u16* __restrict__ wtin, u16* __restrict__ wtl,
    const float* __restrict__ asrc, const float* __restrict__ adst, u16* __restrict__ vmat,
    const int* __restrict__ ei, int* __restrict__ deg,
    const float* __restrict__ ipb, u16* __restrict__ vmatc, float* __restrict__ bias0)
{
  int b = blockIdx.x;
  if (b < 1564){
    // A1: x channels [0,64): thread -> 8 contiguous channels of one node
    int u = b*256 + threadIdx.x;          // < MP*8 = 400384
    int n = u >> 3;
    int c0 = (u & 7) * 8;
    uint4 o = {0u,0u,0u,0u};
    if (n < NN){
      const float* xp = x + (size_t)n*64 + c0;
      float4 v0 = *(const float4*)xp;
      float4 v1 = *(const float4*)(xp + 4);
      o.x = pack2(v0.x, v0.y); o.y = pack2(v0.z, v0.w);
      o.z = pack2(v1.x, v1.y); o.w = pack2(v1.z, v1.w);
    }
    *(uint4*)(feats + (size_t)n*192 + c0) = o;
  } else if (b < 3128){
    // A2: remb channels [64,128)
    int u = (b-1564)*256 + threadIdx.x;
    int n = u >> 3;
    int c0 = (u & 7) * 8;
    uint4 o = {0u,0u,0u,0u};
    if (n < NN){
      const float* rp = remb + (size_t)rid[n]*64 + c0;
      float4 v0 = *(const float4*)rp;
      float4 v1 = *(const float4*)(rp + 4);
      o.x = pack2(v0.x, v0.y); o.y = pack2(v0.z, v0.w);
      o.z = pack2(v1.x, v1.y); o.w = pack2(v1.z, v1.w);
    }
    *(uint4*)(feats + (size_t)n*192 + 64 + c0) = o;
  } else if (b < 4692){
    // A3: posenc channels [128,192)
    int u = (b-3128)*256 + threadIdx.x;
    int n = u >> 3;
    int i0 = (u & 7) * 8;                 // posenc index base, even
    uint4 o = {0u,0u,0u,0u};
    if (n < NN){
      float fn = (float)n;
      float os[8];
      #pragma unroll
      for (int m=0;m<4;++m){
        float rate = exp2f(-(float)(i0 + 2*m) * (1.0f/64.0f) * 13.287712379549449f);
        float s, c;
        __sincosf(fn * rate, &s, &c);     // fast HW path; err ~3e-3 ~ bf16 rounding
        os[2*m] = s; os[2*m+1] = c;
      }
      o.x = pack2(os[0], os[1]); o.y = pack2(os[2], os[3]);
      o.z = pack2(os[4], os[5]); o.w = pack2(os[6], os[7]);
    }
    *(uint4*)(feats + (size_t)n*192 + 128 + i0) = o;
  } else if (b < 5908){
    int idx = (b - 4692)*256 + threadIdx.x;
    if (idx < 49152){
      // wtin[n][k] = (Win@W0)[k][n] = sum_j Win[k][j]*W0[j][n]
      int k = idx >> 8, n = idx & 255;
      const float* wrow = ipw + (size_t)k*256;
      float s = 0.f;
      #pragma unroll 8
      for (int j=0;j<256;++j) s += wrow[j] * gatw[(size_t)j*256 + n];
      wtin[n*192 + k] = f2bf(s);
    } else {
      int j = idx - 49152;          // gat: 4 x [256][256]^T
      if (j < 262144){
        int l = j >> 16, rem = j & 65535;
        int n = rem >> 8, k = rem & 255;
        wtl[j] = f2bf(gatw[l*65536 + k*256 + n]);
      }
    }
  } else if (b < 5972){
    // vmat[l][16][256]: rows 0..3 = W^T·a_src, 4..7 = W^T·a_dst, 8..15 zero
    int idx = (b - 5908)*256 + threadIdx.x;
    if (idx < 16384){
      int l = idx >> 12, rem = idx & 4095, v = rem >> 8, k = rem & 255;
      float s = 0.f;
      if (v < 8){
        const float* a = (v < 4) ? (asrc + l*256 + v*64) : (adst + l*256 + (v-4)*64);
        const float* w = gatw + (size_t)l*65536 + k*256 + (v & 3)*64;
        #pragma unroll 8
        for (int c=0;c<64;++c) s += w[c]*a[c];
      }
      vmat[idx] = f2bf(s);
    }
  } else if (b < 5980){
    // F: vmatc[v][k] = sum_j Win[k][j] * (W0·a_v)[j]   (layer 0 fused scores)
    int v = b - 5972;                // 0..7
    __shared__ float w0a[256];
    int t = threadIdx.x;
    {
      const float* a = (v < 4) ? (asrc + v*64) : (adst + (v-4)*64);
      const float* w = gatw + (size_t)t*256 + (v & 3)*64;
      float s = 0.f;
      #pragma unroll 8
      for (int c=0;c<64;++c) s += w[c]*a[c];
      w0a[t] = s;
    }
    __syncthreads();
    if (t < 192){
      const float* wrow = ipw + (size_t)t*256;
      float s = 0.f;
      #pragma unroll 8
      for (int j=0;j<256;++j) s += wrow[j]*w0a[j];
      vmatc[v*192 + t] = f2bf(s);
      vmatc[(v+8)*192 + t] = 0;      // rows 8..15 zero
    }
  } else if (b < 5981){
    // G: bias0[j] = (b_in@W0)[j]; bias0[256+v] = bias0·a_v (score consts)
    int t = threadIdx.x;
    __shared__ float c0[256];
    {
      float s = 0.f;
      for (int k=0;k<256;++k) s += ipb[k] * gatw[(size_t)k*256 + t];
      c0[t] = s;
      bias0[t] = s;
    }
    __syncthreads();
    if (t < 8){
      const float* a = (t < 4) ? (asrc + t*64) : (adst + (t-4)*64);
      float s = 0.f;
      for (int c=0;c<64;++c) s += c0[(t & 3)*64 + c] * a[c];
      bias0[256 + t] = s;
    }
  } else {
    int i = (b - 5981)*256 + threadIdx.x;
    if (i < ET){
      int d = (i < EE) ? ei[EE + i] : (i - EE);
      atomicAdd(&deg[d], 1);
    }
  }
}

// ---------------- scan1: per-block exclusive scan + block totals ----------------
__global__ void k_scan1(const int* __restrict__ deg, int* __restrict__ row_off, int* __restrict__ part){
  __shared__ int s[256];
  int n = blockIdx.x*256 + threadIdx.x;
  int v = (n < NN) ? deg[n] : 0;
  s[threadIdx.x] = v;
  __syncthreads();
  for (int off=1; off<256; off<<=1){
    int t = (threadIdx.x >= off) ? s[threadIdx.x - off] : 0;
    __syncthreads();
    s[threadIdx.x] += t;
    __syncthreads();
  }
  if (n < NN) row_off[n] = s[threadIdx.x] - v;
  if (threadIdx.x == 255) part[blockIdx.x] = s[255];
}

// ---------------- scan23 ----------------
__global__ void k_scan23(int* __restrict__ row_off, const int* __restrict__ part, int nparts){
  __shared__ int sp[256];
  int t = threadIdx.x;
  sp[t] = (t < nparts && t < (int)blockIdx.x) ? part[t] : 0;
  __syncthreads();
  for (int off=128; off; off>>=1){
    if (t < off) sp[t] += sp[t+off];
    __syncthreads();
  }
  int n = blockIdx.x*256 + t;
  if (n < NN) row_off[n] += sp[0];
}

__global__ void k_scatter(const int* __restrict__ ei, const int* __restrict__ row_off,
                          int* __restrict__ cur, int* __restrict__ csr_src){
  int i = blockIdx.x*blockDim.x + threadIdx.x;
  if (i >= ET) return;
  int s, d;
  if (i < EE){ s = ei[i]; d = ei[EE + i]; } else { s = i - EE; d = i - EE; }
  int pos = row_off[d] + atomicAdd(&cur[d], 1);
  csr_src[pos] = s;
}

// ================ MFMA GEMM, 3-buffer counted-vmcnt K-loop (T4-lite) ================
// C[M][256](bf16) and/or C8[M][256](fp8 e4m3) = A[M][K](bf16) @ Wt[256][K]^T (+bias).
// grid 782 (1D) with bijective chunked XCD transform (m204).
// Latency-bound regime fix (R11 counters: MfmaUtil 4%, Occ 15%): prefetch 2
// K-steps ahead into 3 LDS buffer pairs; barriers wait vmcnt(8/4/0) -- the two
// newest stages stay in flight across the barrier instead of draining to 0
// (old __syncthreads forced vmcnt(0) = full stage latency exposed every step).
// Loop fully unrolled (template K) so waitcnt immediates are compile-time.
template<int K>
__global__ __launch_bounds__(256, 3) void k_gemm(
    const u16* __restrict__ A, const u16* __restrict__ Wt,
    const float* __restrict__ bias, const u16* __restrict__ vmat,
    const float* __restrict__ sbias,
    float* __restrict__ ss, float* __restrict__ sd,
    u16* __restrict__ C, u8* __restrict__ C8, int M)
{
  constexpr int NK = K/32;
  __shared__ u16 Asl[3][128*32];   // 8 KB x3
  __shared__ u16 Bsl[3][128*32];   // 8 KB x3   (48 KB total -> still 3 blocks/CU)
  int tid = threadIdx.x;
  int wave = tid >> 6, lane = tid & 63, quad = lane >> 4, lm = lane & 15;

  // bijective chunked XCD swizzle over nwg=782: q=97, r=6
  int bid0 = blockIdx.x;
  int xcd = bid0 & 7, off = bid0 >> 3;
  const int q = 782 >> 3, r = 782 & 7;
  int wgid = (xcd < r ? xcd*(q+1) : r*(q+1) + (xcd - r)*q) + off;
  int r0 = (wgid >> 1) * 128;
  int cb = wgid & 1;                     // col half of C (0/1)

  int rW = (wave >> 1) * 64;
  int cW = (wave & 1) * 64;
  bool doScore = vmat && (cb == 0) && ((wave & 1) == 0);

  f32x4 acc[4][4] = {};
  f32x4 accs[4] = {};

  auto stage = [&](int buf, int k0){
    for (int m = wave; m < 8; m += 4){
      int s = m*64 + lane;
      int rr = s >> 2, p = s & 3;
      int c = p ^ ((rr >> 2) & 3);
      dma16(A + (size_t)(r0 + rr)*K + k0 + c*8, &Asl[buf][m*512]);
    }
    for (int m = wave; m < 8; m += 4){
      int s = m*64 + lane;
      int rr = s >> 2, p = s & 3;
      int c = p ^ ((rr >> 2) & 3);
      dma16(Wt + (size_t)(cb*128 + rr)*K + k0 + c*8, &Bsl[buf][m*512]);
    }
  };

  // prologue: 2 stages in flight (8 loads/thread)
  stage(0, 0);
  stage(1, 32);

  #pragma unroll
  for (int ks = 0; ks < NK; ++ks){
    int cur = ks % 3;
    if (ks + 2 < NK) stage((ks+2) % 3, (ks+2)*32);   // overwrites buf (ks-1)%3,
                                                     // protected by iter ks-1's end barrier
    // wait only for stage ks: leave the 2 newest stages (8 loads) in flight
    if (ks + 2 < NK)      asm volatile("s_waitcnt vmcnt(8)" ::: "memory");
    else if (ks + 1 < NK) asm volatile("s_waitcnt vmcnt(4)" ::: "memory");
    else                  asm volatile("s_waitcnt vmcnt(0)" ::: "memory");
    __builtin_amdgcn_s_barrier();          // all waves' stage-ks data in LDS
    __builtin_amdgcn_sched_barrier(0);     // fence: no ds_read hoisted above barrier

    bf16x8 a[4], b[4];
    #pragma unroll
    for (int i=0;i<4;++i){
      int row = rW + i*16 + lm;
      int slot = row*4 + (quad ^ ((row >> 2) & 3));
      a[i] = *(const bf16x8*)(&Asl[cur][slot*8]);
    }
    #pragma unroll
    for (int j=0;j<4;++j){
      int row = cW + j*16 + lm;
      int slot = row*4 + (quad ^ ((row >> 2) & 3));
      b[j] = *(const bf16x8*)(&Bsl[cur][slot*8]);
    }
    #pragma unroll
    for (int i=0;i<4;++i)
      #pragma unroll
      for (int j=0;j<4;++j)
        acc[i][j] = __builtin_amdgcn_mfma_f32_16x16x32_bf16(a[i], b[j], acc[i][j], 0, 0, 0);
    if (doScore){
      bf16x8 bs = *(const bf16x8*)(vmat + (size_t)lm*K + ks*32 + quad*8);
      #pragma unroll
      for (int i=0;i<4;++i)
        accs[i] = __builtin_amdgcn_mfma_f32_16x16x32_bf16(a[i], bs, accs[i], 0, 0, 0);
    }
    __builtin_amdgcn_sched_barrier(0);     // fence: reads/MFMA stay above barrier
    __builtin_amdgcn_s_barrier();          // all waves done reading buf cur ->
                                           // next iter may restage it
  }

  // scores: C/D layout col=lane&15, row=quad*4+reg  [verified m89/m91]
  if (doScore){
    float sb = sbias ? sbias[lm & 7] : 0.f;
    #pragma unroll
    for (int i=0;i<4;++i){
      #pragma unroll
      for (int r2=0;r2<4;++r2){
        int row = r0 + rW + i*16 + quad*4 + r2;
        if (row < M){
          float sv = accs[i][r2] + sb;
          if (lm < 4)      ss[row*4 + lm]     = sv;
          else if (lm < 8) sd[row*4 + lm - 4] = sv;
        }
      }
    }
  }

  // epilogue: direct stores (bf16 and/or fp8)
  #pragma unroll
  for (int i=0;i<4;++i){
    #pragma unroll
    for (int r2=0;r2<4;++r2){
      int row = r0 + rW + i*16 + quad*4 + r2;
      if (row < M){
        #pragma unroll
        for (int j=0;j<4;++j){
          int col = cb*128 + cW + j*16 + lm;
          float v = acc[i][j][r2];
          if (bias) v += bias[col];
          if (C)  C[(size_t)row*256 + col] = f2bf(v);
          if (C8) C8[(size_t)row*256 + col] = f2fp8(v);
        }
      }
    }
  }
}

// ---------------- fused GAT aggregate + bias + relu + layernorm ----------------
// 4 NODES PER WAVE: 16 lanes x 16 fp8 channels (uint4 = 16 B/lane); one gather
// instruction fetches four 256 B rows. TWO-LEVEL software pipeline: indices for
// pair j+1 loaded one iteration EARLY, so the row gather at iter j uses
// register-resident indices; index loads for pair j+2 issue in parallel.
// Per-node pair order and arithmetic identical -> bitwise-stable absmax.
__global__ __launch_bounds__(256) void k_aggregate(
    const u8* __restrict__ h8, const float* __restrict__ ssrc, const float* __restrict__ sdst,
    const int* __restrict__ row_off, const int* __restrict__ deg, const int* __restrict__ csr_src,
    const float* __restrict__ bias, const float* __restrict__ g, const float* __restrict__ bb,
    u16* __restrict__ hout, u8* __restrict__ hout8)
{
  int wv = (blockIdx.x*blockDim.x + threadIdx.x) >> 6;
  int lane = threadIdx.x & 63;
  int sub = lane >> 4;             // node slot within wave (0..3)
  int ql  = lane & 15;             // lane within node group
  int n = wv*4 + sub;              // 3125 blocks * 4 waves * 4 = 50000 exactly
  if (n >= NN) return;
  int c0 = ql*16;                  // 16 consecutive channels per lane
  int head = ql >> 2;
  float sdh = sdst[n*4 + head];
  int ro = row_off[n];
  int dg = deg[n];                 // >= 1 (self loop)
  float denA = 0.f, denB = 0.f;
  float a[16] = {};
  float b[16] = {};

  // prologue: rows/scores for pair 0 + indices for pair 1 (dummy 0 past end)
  int sA = csr_src[ro];
  int sB = (1 < dg) ? csr_src[ro + 1] : 0;
  uint4 uA = *(const uint4*)(h8 + (size_t)sA*HIDD + c0);
  uint4 uB = *(const uint4*)(h8 + (size_t)sB*HIDD + c0);
  float fA = ssrc[sA*4 + head];
  float fB = ssrc[sB*4 + head];
  int nA1 = (2 < dg) ? csr_src[ro + 2] : 0;
  int nB1 = (3 < dg) ? csr_src[ro + 3] : 0;

  for (int j = 0; j < dg; j += 2){
    // issue next pair's rows/scores from REGISTER-resident indices (no dep)
    uint4 vA = *(const uint4*)(h8 + (size_t)nA1*HIDD + c0);
    uint4 vB = *(const uint4*)(h8 + (size_t)nB1*HIDD + c0);
    float gA = ssrc[nA1*4 + head];
    float gB = ssrc[nB1*4 + head];
    // issue indices for the pair after next (consumed next iteration)
    int nA2 = (j + 4 < dg) ? csr_src[ro + j + 4] : 0;
    int nB2 = (j + 5 < dg) ? csr_src[ro + j + 5] : 0;

    // compute current A (always valid)
    float eA = fA + sdh;
    eA = (eA > 0.f) ? eA : 0.2f*eA;
    float xA = __expf(eA);
    denA += xA;
    {
      f32x2 p0 = __builtin_amdgcn_cvt_pk_f32_fp8((int)uA.x, false);
      f32x2 p1 = __builtin_amdgcn_cvt_pk_f32_fp8((int)uA.x, true);
      f32x2 p2 = __builtin_amdgcn_cvt_pk_f32_fp8((int)uA.y, false);
      f32x2 p3 = __builtin_amdgcn_cvt_pk_f32_fp8((int)uA.y, true);
      f32x2 p4 = __builtin_amdgcn_cvt_pk_f32_fp8((int)uA.z, false);
      f32x2 p5 = __builtin_amdgcn_cvt_pk_f32_fp8((int)uA.z, true);
      f32x2 p6 = __builtin_amdgcn_cvt_pk_f32_fp8((int)uA.w, false);
      f32x2 p7 = __builtin_amdgcn_cvt_pk_f32_fp8((int)uA.w, true);
      a[0]+=xA*p0.x; a[1]+=xA*p0.y; a[2]+=xA*p1.x; a[3]+=xA*p1.y;
      a[4]+=xA*p2.x; a[5]+=xA*p2.y; a[6]+=xA*p3.x; a[7]+=xA*p3.y;
      a[8]+=xA*p4.x; a[9]+=xA*p4.y; a[10]+=xA*p5.x; a[11]+=xA*p5.y;
      a[12]+=xA*p6.x; a[13]+=xA*p6.y; a[14]+=xA*p7.x; a[15]+=xA*p7.y;
    }
    // compute current B (weight 0 past the tail)
    float eB = fB + sdh;
    eB = (eB > 0.f) ? eB : 0.2f*eB;
    float xB = (j + 1 < dg) ? __expf(eB) : 0.f;
    denB += xB;
    {
      f32x2 p0 = __builtin_amdgcn_cvt_pk_f32_fp8((int)uB.x, false);
      f32x2 p1 = __builtin_amdgcn_cvt_pk_f32_fp8((int)uB.x, true);
      f32x2 p2 = __builtin_amdgcn_cvt_pk_f32_fp8((int)uB.y, false);
      f32x2 p3 = __builtin_amdgcn_cvt_pk_f32_fp8((int)uB.y, true);
      f32x2 p4 = __builtin_amdgcn_cvt_pk_f32_fp8((int)uB.z, false);
      f32x2 p5 = __builtin_amdgcn_cvt_pk_f32_fp8((int)uB.z, true);
      f32x2 p6 = __builtin_amdgcn_cvt_pk_f32_fp8((int)uB.w, false);
      f32x2 p7 = __builtin_amdgcn_cvt_pk_f32_fp8((int)uB.w, true);
      b[0]+=xB*p0.x; b[1]+=xB*p0.y; b[2]+=xB*p1.x; b[3]+=xB*p1.y;
      b[4]+=xB*p2.x; b[5]+=xB*p2.y; b[6]+=xB*p3.x; b[7]+=xB*p3.y;
      b[8]+=xB*p4.x; b[9]+=xB*p4.y; b[10]+=xB*p5.x; b[11]+=xB*p5.y;
      b[12]+=xB*p6.x; b[13]+=xB*p6.y; b[14]+=xB*p7.x; b[15]+=xB*p7.y;
    }
    uA = vA; uB = vB; fA = gA; fB = gB; nA1 = nA2; nB1 = nB2;
  }

  float inv = 1.f / (denA + denB);
  float y[16];
  float4 bi[4];
  #pragma unroll
  for (int m=0;m<4;++m) bi[m] = *(const float4*)(bias + c0 + m*4);
  #pragma unroll
  for (int k=0;k<16;++k){
    float bv = ((const float*)bi)[k];
    y[k] = fmaxf((a[k]+b[k])*inv + bv, 0.f);
  }
  // layernorm over 256 channels within the 16-lane group (xor-closed, offsets 1..8)
  float sum = 0.f;
  #pragma unroll
  for (int k=0;k<16;++k) sum += y[k];
  #pragma unroll
  for (int o=8;o>=1;o>>=1) sum += __shfl_xor(sum, o);
  float mu = sum * (1.f/256.f);
  float d[16], sq = 0.f;
  #pragma unroll
  for (int k=0;k<16;++k){ d[k] = y[k]-mu; sq += d[k]*d[k]; }
  #pragma unroll
  for (int o=8;o>=1;o>>=1) sq += __shfl_xor(sq, o);
  float rs = rsqrtf(sq*(1.f/256.f) + LN_EPSF);
  float4 gv[4], qv[4];
  #pragma unroll
  for (int m=0;m<4;++m){
    gv[m] = *(const float4*)(g + c0 + m*4);
    qv[m] = *(const float4*)(bb + c0 + m*4);
  }
  float o16[16];
  #pragma unroll
  for (int k=0;k<16;++k)
    o16[k] = d[k]*rs*((const float*)gv)[k] + ((const float*)qv)[k];

  if (hout8){
    uint4 w;
    u32 w0 = (u32)__builtin_amdgcn_cvt_pk_fp8_f32(o16[0], o16[1], 0, false);
    w.x = (u32)__builtin_amdgcn_cvt_pk_fp8_f32(o16[2], o16[3], (int)w0, true);
    w0 = (u32)__builtin_amdgcn_cvt_pk_fp8_f32(o16[4], o16[5], 0, false);
    w.y = (u32)__builtin_amdgcn_cvt_pk_fp8_f32(o16[6], o16[7], (int)w0, true);
    w0 = (u32)__builtin_amdgcn_cvt_pk_fp8_f32(o16[8], o16[9], 0, false);
    w.z = (u32)__builtin_amdgcn_cvt_pk_fp8_f32(o16[10], o16[11], (int)w0, true);
    w0 = (u32)__builtin_amdgcn_cvt_pk_fp8_f32(o16[12], o16[13], 0, false);
    w.w = (u32)__builtin_amdgcn_cvt_pk_fp8_f32(o16[14], o16[15], (int)w0, true);
    *(uint4*)(hout8 + (size_t)n*HIDD + c0) = w;
  } else {
    uint4 o4a, o4b;
    o4a.x = pack2(o16[0], o16[1]);  o4a.y = pack2(o16[2], o16[3]);
    o4a.z = pack2(o16[4], o16[5]);  o4a.w = pack2(o16[6], o16[7]);
    o4b.x = pack2(o16[8], o16[9]);  o4b.y = pack2(o16[10], o16[11]);
    o4b.z = pack2(o16[12], o16[13]); o4b.w = pack2(o16[14], o16[15]);
    *(uint4*)(hout + (size_t)n*HIDD + c0) = o4a;
    *(uint4*)(hout + (size_t)n*HIDD + c0 + 8) = o4b;
  }
}

// ---------------- global mean pool (fp8 input): 1000 blocks, run-length atomics ----------------
__global__ __launch_bounds__(256) void k_pool(
    const u8* __restrict__ h8, const int* __restrict__ batch,
    float* __restrict__ pooled, float* __restrict__ cnt)
{
  const int chunk = 50;  // 1000*50 >= NN
  int t = threadIdx.x;
  int n0 = blockIdx.x*chunk;
  int n1 = min(n0 + chunk, NN);
  if (n0 >= n1) return;
  float acc = 0.f;
  int curb = batch[n0];
  int runStart = n0;
  bool hi = (t & 2) != 0;
  for (int n=n0; n<n1; ++n){
    int b = batch[n];
    if (b != curb){
      atomicAdd(&pooled[curb*HIDD + t], acc);
      if (t == 0) atomicAdd(&cnt[curb], (float)(n - runStart));
      acc = 0.f; curb = b; runStart = n;
    }
    u32 w = *(const u32*)(h8 + (size_t)n*HIDD + (t & ~3));
    f32x2 p = hi ? __builtin_amdgcn_cvt_pk_f32_fp8((int)w, true)
                 : __builtin_amdgcn_cvt_pk_f32_fp8((int)w, false);  // word-sel must be const
    acc += (t & 1) ? p.y : p.x;
  }
  atomicAdd(&pooled[curb*HIDD + t], acc);
  if (t == 0) atomicAdd(&cnt[curb], (float)(n1 - runStart));
}

// ---------------- readout: gelu(pooled@W1+b1)@W2+b2 (fp32, tiny) ----------------
__global__ __launch_bounds__(256) void k_readout(
    const float* __restrict__ pooled, const float* __restrict__ cnt,
    const float* __restrict__ w1, const float* __restrict__ b1,
    const float* __restrict__ w2, const float* __restrict__ b2,
    float* __restrict__ out)
{
  __shared__ float p[256], mid[256];
  int b = blockIdx.x, t = threadIdx.x;
  float c = fmaxf(cnt[b], 1.f);
  p[t] = pooled[b*HIDD + t] / c;
  __syncthreads();
  float acc = b1[t];
  for (int k=0;k<256;++k) acc += p[k]*w1[k*256+t];
  mid[t] = 0.5f*acc*(1.f + erff(acc*0.70710678118654752f));
  __syncthreads();
  float acc2 = b2[t];
  for (int k=0;k<256;++k) acc2 += mid[k]*w2[k*256+t];
  out[b*HIDD + t] = acc2;
}

extern "C" void kernel_launch(void* const* d_in, const int* in_sizes, int n_in,
                              void* d_out, int out_size, void* d_ws, size_t ws_size,
                              hipStream_t stream)
{
  const float* x    = (const float*)d_in[0];
  const float* remb = (const float*)d_in[1];
  const float* ipw  = (const float*)d_in[2];
  const float* ipb  = (const float*)d_in[3];
  const float* gatw = (const float*)d_in[4];
  const float* asrc = (const float*)d_in[5];
  const float* adst = (const float*)d_in[6];
  const float* gatb = (const float*)d_in[7];
  const float* lng  = (const float*)d_in[8];
  const float* lnb  = (const float*)d_in[9];
  const float* row1 = (const float*)d_in[10];
  const float* rob1 = (const float*)d_in[11];
  const float* row2 = (const float*)d_in[12];
  const float* rob2 = (const float*)d_in[13];
  const int* ei   = (const int*)d_in[14];
  const int* batch= (const int*)d_in[15];
  const int* rid  = (const int*)d_in[16];

  char* ws = (char*)d_ws;
  int*   deg  = (int*)  (ws + 0);          // 200192
  int*   cur  = (int*)  (ws + 200192);     // 200192
  float* cnt  = (float*)(ws + 400384);     // 256
  float* pool = (float*)(ws + 400640);     // 16384
  // ZERO_BYTES = 417024
  int*   row  = (int*)  (ws + 417024);     // 200192
  int*   part = (int*)  (ws + 617216);     // 1024
  int*   csr  = (int*)  (ws + 618240);     // 1800192 -> 2418432
  float* ss   = (float*)(ws + 2418432);    // 800768
  float* sd   = (float*)(ws + 3219200);    // 800768  -> 4019968
  u16*   vmat = (u16*)  (ws + 4019968);    // 32768   -> 4052736
  u16*   feats= (u16*)  (ws + 4052736);    // 19218432-> 23271168
  u16*   wtin = (u16*)  (ws + 23271168);   // 98304   -> 23369472  (fused (Win@W0)^T)
  u16*   wtl  = (u16*)  (ws + 23369472);   // 524288  -> 23893760
  u16*   hA   = (u16*)  (ws + 23893760);   // 25624576-> 49518336  (bf16 h / fp8 final)
  u8*    hA8  = (u8*)   (ws + 23893760);   // alias: final-layer fp8 h
  u8*    hB8  = (u8*)   (ws + 49518336);   // 12812288-> 62330624
  u16*   vmatc= (u16*)  (ws + 62330624);   // 6144    -> 62336768  (fused layer-0 scores)
  float* bias0= (float*)(ws + 62336768);   // 1056    -> 62337824  ([0,256)=bias, [256,264)=score consts)

  (void)hipMemsetAsync(ws, 0, 417024, stream);

  k_setup <<<7739, 256, 0, stream>>>(x, remb, rid, feats, ipw, gatw, wtin, wtl,
                                     asrc, adst, vmat, ei, deg, ipb, vmatc, bias0);
  k_scan1 <<<196, 256, 0, stream>>>(deg, row, part);
  k_scan23<<<196, 256, 0, stream>>>(row, part, 196);
  k_scatter<<<1758, 256, 0, stream>>>(ei, row, cur, csr);

  // layer 0 (fused inproj): feats@(Win@W0) + b_in@W0 -> hB8 + scores
  k_gemm<KIN><<<782, 256, 0, stream>>>(feats, wtin, bias0, vmatc, bias0 + 256,
                                       ss, sd, nullptr, hB8, NN);
  k_aggregate<<<3125, 256, 0, stream>>>(hB8, ss, sd, row, deg, csr,
                                        gatb + 0*HIDD, lng + 0*HIDD, lnb + 0*HIDD,
                                        hA, nullptr);

  for (int l = 1; l < 4; ++l){
    k_gemm<HIDD><<<782, 256, 0, stream>>>(hA, wtl + (size_t)l*HIDD*HIDD, nullptr,
                                          vmat + (size_t)l*16*256, nullptr,
                                          ss, sd, nullptr, hB8, NN);
    if (l < 3){
      k_aggregate<<<3125, 256, 0, stream>>>(hB8, ss, sd, row, deg, csr,
                                            gatb + l*HIDD, lng + l*HIDD, lnb + l*HIDD,
                                            hA, nullptr);
    } else {
      // final layer: write fp8 (pool decodes) — halves pool read + agg write traffic
      k_aggregate<<<3125, 256, 0, stream>>>(hB8, ss, sd, row, deg, csr,
                                            gatb + l*HIDD, lng + l*HIDD, lnb + l*HIDD,
                                            nullptr, hA8);
    }
  }

  k_pool   <<<1000, 256, 0, stream>>>(hA8, batch, pool, cnt);
  k_readout<<<16, 256, 0, stream>>>(pool, cnt, row1, rob1, row2, rob2, (float*)d_out);
}

// Round 13
// 430.293 us; speedup vs baseline: 1.0144x; 1.0144x over previous
//
#include <hip/hip_runtime.h>
#include <cmath>

typedef unsigned short u16;
typedef unsigned char u8;
typedef unsigned int u32;
typedef short bf16x8 __attribute__((ext_vector_type(8)));
typedef float f32x4 __attribute__((ext_vector_type(4)));
typedef float f32x2 __attribute__((ext_vector_type(2)));

#define NN 50000      // nodes
#define MP 50048      // padded to 128*391
#define EE 400000     // raw edges
#define ET 450000     // edges + self loops
#define HIDD 256
#define KIN 192       // 3*F
#define LN_EPSF 1e-5f

__device__ __forceinline__ float bf2f(u16 u){ return __uint_as_float(((u32)u)<<16); }
__device__ __forceinline__ u16 f2bf(float f){
  u32 x = __float_as_uint(f);
  u32 r = x + 0x7fffu + ((x>>16)&1u);   // RNE
  return (u16)(r>>16);
}
__device__ __forceinline__ u32 pack2(float a, float b){ return (u32)f2bf(a) | ((u32)f2bf(b)<<16); }
__device__ __forceinline__ u8 f2fp8(float v){
  return (u8)(__builtin_amdgcn_cvt_pk_fp8_f32(v, v, 0, false) & 0xff);  // OCP e4m3, RNE+sat
}

__device__ __forceinline__ void dma16(const u16* g, u16* lds){
  __builtin_amdgcn_global_load_lds(
      (const __attribute__((address_space(1))) void*)g,
      (__attribute__((address_space(3))) void*)lds, 16, 0, 0);
}

// ================ merged setup ================
// Inproj GEMM is algebraically fused into layer 0:
//   h0 = feats@(Win@W0) + b_in@W0 ; scores0 = feats@(Win·(W0·a)) + (b_in@W0)·a
// Block partition:
//   [0,1564)     A1: feats x-part      (MP*8 vec8 units)
//   [1564,3128)  A2: feats remb-part
//   [3128,4692)  A3: feats posenc-part
//   [4692,5908)  B : wtin = (Win@W0)^T (fused, 256-dot each) | wtl transposes
//   [5908,5972)  C : vmat (layers; l=0 slot unused)
//   [5972,5980)  F : vmatc[16][192] = Win·(W0·a) fused score mat (8 blocks)
//   [5980,5981)  G : bias0[256] = b_in@W0 ; bias0[256..264) = score consts
//   [5981,7739)  D : degree atomics    (ET elems)
__global__ __launch_bounds__(256) void k_setup(
    const float* __restrict__ x, const float* __restrict__ remb, const int* __restrict__ rid,
    u16* __restrict__ feats,
    const float* __restrict__ ipw, const float* __restrict__ gatw,
    u16* __restrict__ wtin, u16* __restrict__ wtl,
    const float* __restrict__ asrc, const float* __restrict__ adst, u16* __restrict__ vmat,
    const int* __restrict__ ei, int* __restrict__ deg,
    const float* __restrict__ ipb, u16* __restrict__ vmatc, float* __restrict__ bias0)
{
  int b = blockIdx.x;
  if (b < 1564){
    // A1: x channels [0,64): thread -> 8 contiguous channels of one node
    int u = b*256 + threadIdx.x;          // < MP*8 = 400384
    int n = u >> 3;
    int c0 = (u & 7) * 8;
    uint4 o = {0u,0u,0u,0u};
    if (n < NN){
      const float* xp = x + (size_t)n*64 + c0;
      float4 v0 = *(const float4*)xp;
      float4 v1 = *(const float4*)(xp + 4);
      o.x = pack2(v0.x, v0.y); o.y = pack2(v0.z, v0.w);
      o.z = pack2(v1.x, v1.y); o.w = pack2(v1.z, v1.w);
    }
    *(uint4*)(feats + (size_t)n*192 + c0) = o;
  } else if (b < 3128){
    // A2: remb channels [64,128)
    int u = (b-1564)*256 + threadIdx.x;
    int n = u >> 3;
    int c0 = (u & 7) * 8;
    uint4 o = {0u,0u,0u,0u};
    if (n < NN){
      const float* rp = remb + (size_t)rid[n]*64 + c0;
      float4 v0 = *(const float4*)rp;
      float4 v1 = *(const float4*)(rp + 4);
      o.x = pack2(v0.x, v0.y); o.y = pack2(v0.z, v0.w);
      o.z = pack2(v1.x, v1.y); o.w = pack2(v1.z, v1.w);
    }
    *(uint4*)(feats + (size_t)n*192 + 64 + c0) = o;
  } else if (b < 4692){
    // A3: posenc channels [128,192)
    int u = (b-3128)*256 + threadIdx.x;
    int n = u >> 3;
    int i0 = (u & 7) * 8;                 // posenc index base, even
    uint4 o = {0u,0u,0u,0u};
    if (n < NN){
      float fn = (float)n;
      float os[8];
      #pragma unroll
      for (int m=0;m<4;++m){
        float rate = exp2f(-(float)(i0 + 2*m) * (1.0f/64.0f) * 13.287712379549449f);
        float s, c;
        __sincosf(fn * rate, &s, &c);     // fast HW path; err ~3e-3 ~ bf16 rounding
        os[2*m] = s; os[2*m+1] = c;
      }
      o.x = pack2(os[0], os[1]); o.y = pack2(os[2], os[3]);
      o.z = pack2(os[4], os[5]); o.w = pack2(os[6], os[7]);
    }
    *(uint4*)(feats + (size_t)n*192 + 128 + i0) = o;
  } else if (b < 5908){
    int idx = (b - 4692)*256 + threadIdx.x;
    if (idx < 49152){
      // wtin[n][k] = (Win@W0)[k][n] = sum_j Win[k][j]*W0[j][n]
      int k = idx >> 8, n = idx & 255;
      const float* wrow = ipw + (size_t)k*256;
      float s = 0.f;
      #pragma unroll 8
      for (int j=0;j<256;++j) s += wrow[j] * gatw[(size_t)j*256 + n];
      wtin[n*192 + k] = f2bf(s);
    } else {
      int j = idx - 49152;          // gat: 4 x [256][256]^T
      if (j < 262144){
        int l = j >> 16, rem = j & 65535;
        int n = rem >> 8, k = rem & 255;
        wtl[j] = f2bf(gatw[l*65536 + k*256 + n]);
      }
    }
  } else if (b < 5972){
    // vmat[l][16][256]: rows 0..3 = W^T·a_src, 4..7 = W^T·a_dst, 8..15 zero
    int idx = (b - 5908)*256 + threadIdx.x;
    if (idx < 16384){
      int l = idx >> 12, rem = idx & 4095, v = rem >> 8, k = rem & 255;
      float s = 0.f;
      if (v < 8){
        const float* a = (v < 4) ? (asrc + l*256 + v*64) : (adst + l*256 + (v-4)*64);
        const float* w = gatw + (size_t)l*65536 + k*256 + (v & 3)*64;
        #pragma unroll 8
        for (int c=0;c<64;++c) s += w[c]*a[c];
      }
      vmat[idx] = f2bf(s);
    }
  } else if (b < 5980){
    // F: vmatc[v][k] = sum_j Win[k][j] * (W0·a_v)[j]   (layer 0 fused scores)
    int v = b - 5972;                // 0..7
    __shared__ float w0a[256];
    int t = threadIdx.x;
    {
      const float* a = (v < 4) ? (asrc + v*64) : (adst + (v-4)*64);
      const float* w = gatw + (size_t)t*256 + (v & 3)*64;
      float s = 0.f;
      #pragma unroll 8
      for (int c=0;c<64;++c) s += w[c]*a[c];
      w0a[t] = s;
    }
    __syncthreads();
    if (t < 192){
      const float* wrow = ipw + (size_t)t*256;
      float s = 0.f;
      #pragma unroll 8
      for (int j=0;j<256;++j) s += wrow[j]*w0a[j];
      vmatc[v*192 + t] = f2bf(s);
      vmatc[(v+8)*192 + t] = 0;      // rows 8..15 zero
    }
  } else if (b < 5981){
    // G: bias0[j] = (b_in@W0)[j]; bias0[256+v] = bias0·a_v (score consts)
    int t = threadIdx.x;
    __shared__ float c0[256];
    {
      float s = 0.f;
      for (int k=0;k<256;++k) s += ipb[k] * gatw[(size_t)k*256 + t];
      c0[t] = s;
      bias0[t] = s;
    }
    __syncthreads();
    if (t < 8){
      const float* a = (t < 4) ? (asrc + t*64) : (adst + (t-4)*64);
      float s = 0.f;
      for (int c=0;c<64;++c) s += c0[(t & 3)*64 + c] * a[c];
      bias0[256 + t] = s;
    }
  } else {
    int i = (b - 5981)*256 + threadIdx.x;
    if (i < ET){
      int d = (i < EE) ? ei[EE + i] : (i - EE);
      atomicAdd(&deg[d], 1);
    }
  }
}

// ---------------- scan1: per-block exclusive scan + block totals ----------------
__global__ void k_scan1(const int* __restrict__ deg, int* __restrict__ row_off, int* __restrict__ part){
  __shared__ int s[256];
  int n = blockIdx.x*256 + threadIdx.x;
  int v = (n < NN) ? deg[n] : 0;
  s[threadIdx.x] = v;
  __syncthreads();
  for (int off=1; off<256; off<<=1){
    int t = (threadIdx.x >= off) ? s[threadIdx.x - off] : 0;
    __syncthreads();
    s[threadIdx.x] += t;
    __syncthreads();
  }
  if (n < NN) row_off[n] = s[threadIdx.x] - v;
  if (threadIdx.x == 255) part[blockIdx.x] = s[255];
}

// ---------------- scan23 ----------------
__global__ void k_scan23(int* __restrict__ row_off, const int* __restrict__ part, int nparts){
  __shared__ int sp[256];
  int t = threadIdx.x;
  sp[t] = (t < nparts && t < (int)blockIdx.x) ? part[t] : 0;
  __syncthreads();
  for (int off=128; off; off>>=1){
    if (t < off) sp[t] += sp[t+off];
    __syncthreads();
  }
  int n = blockIdx.x*256 + t;
  if (n < NN) row_off[n] += sp[0];
}

__global__ void k_scatter(const int* __restrict__ ei, const int* __restrict__ row_off,
                          int* __restrict__ cur, int* __restrict__ csr_src){
  int i = blockIdx.x*blockDim.x + threadIdx.x;
  if (i >= ET) return;
  int s, d;
  if (i < EE){ s = ei[i]; d = ei[EE + i]; } else { s = i - EE; d = i - EE; }
  int pos = row_off[d] + atomicAdd(&cur[d], 1);
  csr_src[pos] = s;
}

// ================ m97-style MFMA GEMM, double-buffered K-loop ================
// C[M][256](bf16) and/or C8[M][256](fp8 e4m3) = A[M][K](bf16) @ Wt[256][K]^T (+bias).
// grid 782 (1D) with bijective chunked XCD transform (m204): both col-halves of a
// row-tile land on the same XCD -> shared A-panel L2-hits the second time.
// sbias: per-head additive score constant (fused inproj bias), may be null.
// NOTE: 3-buffer counted-vmcnt variant (R12) measured +3.2 us -- keep 2-buffer.
template<int K>
__global__ __launch_bounds__(256, 3) void k_gemm(
    const u16* __restrict__ A, const u16* __restrict__ Wt,
    const float* __restrict__ bias, const u16* __restrict__ vmat,
    const float* __restrict__ sbias,
    float* __restrict__ ss, float* __restrict__ sd,
    u16* __restrict__ C, u8* __restrict__ C8, int M)
{
  __shared__ u16 Asl[2][128*32];   // 8 KB x2
  __shared__ u16 Bsl[2][128*32];   // 8 KB x2
  int tid = threadIdx.x;
  int wave = tid >> 6, lane = tid & 63, quad = lane >> 4, lm = lane & 15;

  // bijective chunked XCD swizzle over nwg=782: q=97, r=6
  int bid0 = blockIdx.x;
  int xcd = bid0 & 7, off = bid0 >> 3;
  const int q = 782 >> 3, r = 782 & 7;
  int wgid = (xcd < r ? xcd*(q+1) : r*(q+1) + (xcd - r)*q) + off;
  int r0 = (wgid >> 1) * 128;
  int cb = wgid & 1;                     // col half of C (0/1)

  int rW = (wave >> 1) * 64;
  int cW = (wave & 1) * 64;
  bool doScore = vmat && (cb == 0) && ((wave & 1) == 0);

  f32x4 acc[4][4] = {};
  f32x4 accs[4] = {};

  auto stage = [&](int buf, int k0){
    for (int m = wave; m < 8; m += 4){
      int s = m*64 + lane;
      int rr = s >> 2, p = s & 3;
      int c = p ^ ((rr >> 2) & 3);
      dma16(A + (size_t)(r0 + rr)*K + k0 + c*8, &Asl[buf][m*512]);
    }
    for (int m = wave; m < 8; m += 4){
      int s = m*64 + lane;
      int rr = s >> 2, p = s & 3;
      int c = p ^ ((rr >> 2) & 3);
      dma16(Wt + (size_t)(cb*128 + rr)*K + k0 + c*8, &Bsl[buf][m*512]);
    }
  };

  stage(0, 0);
  __syncthreads();

  for (int ks = 0; ks < K/32; ++ks){
    int cur = ks & 1;
    if (ks + 1 < K/32) stage(cur ^ 1, (ks+1)*32);

    bf16x8 a[4], b[4];
    #pragma unroll
    for (int i=0;i<4;++i){
      int row = rW + i*16 + lm;
      int slot = row*4 + (quad ^ ((row >> 2) & 3));
      a[i] = *(const bf16x8*)(&Asl[cur][slot*8]);
    }
    #pragma unroll
    for (int j=0;j<4;++j){
      int row = cW + j*16 + lm;
      int slot = row*4 + (quad ^ ((row >> 2) & 3));
      b[j] = *(const bf16x8*)(&Bsl[cur][slot*8]);
    }
    #pragma unroll
    for (int i=0;i<4;++i)
      #pragma unroll
      for (int j=0;j<4;++j)
        acc[i][j] = __builtin_amdgcn_mfma_f32_16x16x32_bf16(a[i], b[j], acc[i][j], 0, 0, 0);
    if (doScore){
      bf16x8 bs = *(const bf16x8*)(vmat + (size_t)lm*K + ks*32 + quad*8);
      #pragma unroll
      for (int i=0;i<4;++i)
        accs[i] = __builtin_amdgcn_mfma_f32_16x16x32_bf16(a[i], bs, accs[i], 0, 0, 0);
    }
    __syncthreads();   // drains next-step dma; protects cur buf before restage
  }

  // scores: C/D layout col=lane&15, row=quad*4+reg  [verified m89/m91]
  if (doScore){
    float sb = sbias ? sbias[lm & 7] : 0.f;
    #pragma unroll
    for (int i=0;i<4;++i){
      #pragma unroll
      for (int r2=0;r2<4;++r2){
        int row = r0 + rW + i*16 + quad*4 + r2;
        if (row < M){
          float sv = accs[i][r2] + sb;
          if (lm < 4)      ss[row*4 + lm]     = sv;
          else if (lm < 8) sd[row*4 + lm - 4] = sv;
        }
      }
    }
  }

  // epilogue: direct stores (bf16 and/or fp8)
  #pragma unroll
  for (int i=0;i<4;++i){
    #pragma unroll
    for (int r2=0;r2<4;++r2){
      int row = r0 + rW + i*16 + quad*4 + r2;
      if (row < M){
        #pragma unroll
        for (int j=0;j<4;++j){
          int col = cb*128 + cW + j*16 + lm;
          float v = acc[i][j][r2];
          if (bias) v += bias[col];
          if (C)  C[(size_t)row*256 + col] = f2bf(v);
          if (C8) C8[(size_t)row*256 + col] = f2fp8(v);
        }
      }
    }
  }
}

// ---------------- fused GAT aggregate + bias + relu + layernorm ----------------
// 4 NODES PER WAVE: 16 lanes x 16 fp8 channels (uint4 = 16 B/lane); one gather
// instruction fetches four 256 B rows. TWO-LEVEL software pipeline: indices for
// pair j+1 loaded one iteration EARLY, so the row gather at iter j uses
// register-resident indices; index loads for pair j+2 issue in parallel.
// Per-node pair order and arithmetic identical -> bitwise-stable absmax.
__global__ __launch_bounds__(256) void k_aggregate(
    const u8* __restrict__ h8, const float* __restrict__ ssrc, const float* __restrict__ sdst,
    const int* __restrict__ row_off, const int* __restrict__ deg, const int* __restrict__ csr_src,
    const float* __restrict__ bias, const float* __restrict__ g, const float* __restrict__ bb,
    u16* __restrict__ hout, u8* __restrict__ hout8)
{
  int wv = (blockIdx.x*blockDim.x + threadIdx.x) >> 6;
  int lane = threadIdx.x & 63;
  int sub = lane >> 4;             // node slot within wave (0..3)
  int ql  = lane & 15;             // lane within node group
  int n = wv*4 + sub;              // 3125 blocks * 4 waves * 4 = 50000 exactly
  if (n >= NN) return;
  int c0 = ql*16;                  // 16 consecutive channels per lane
  int head = ql >> 2;
  float sdh = sdst[n*4 + head];
  int ro = row_off[n];
  int dg = deg[n];                 // >= 1 (self loop)
  float denA = 0.f, denB = 0.f;
  float a[16] = {};
  float b[16] = {};

  // prologue: rows/scores for pair 0 + indices for pair 1 (dummy 0 past end)
  int sA = csr_src[ro];
  int sB = (1 < dg) ? csr_src[ro + 1] : 0;
  uint4 uA = *(const uint4*)(h8 + (size_t)sA*HIDD + c0);
  uint4 uB = *(const uint4*)(h8 + (size_t)sB*HIDD + c0);
  float fA = ssrc[sA*4 + head];
  float fB = ssrc[sB*4 + head];
  int nA1 = (2 < dg) ? csr_src[ro + 2] : 0;
  int nB1 = (3 < dg) ? csr_src[ro + 3] : 0;

  for (int j = 0; j < dg; j += 2){
    // issue next pair's rows/scores from REGISTER-resident indices (no dep)
    uint4 vA = *(const uint4*)(h8 + (size_t)nA1*HIDD + c0);
    uint4 vB = *(const uint4*)(h8 + (size_t)nB1*HIDD + c0);
    float gA = ssrc[nA1*4 + head];
    float gB = ssrc[nB1*4 + head];
    // issue indices for the pair after next (consumed next iteration)
    int nA2 = (j + 4 < dg) ? csr_src[ro + j + 4] : 0;
    int nB2 = (j + 5 < dg) ? csr_src[ro + j + 5] : 0;

    // compute current A (always valid)
    float eA = fA + sdh;
    eA = (eA > 0.f) ? eA : 0.2f*eA;
    float xA = __expf(eA);
    denA += xA;
    {
      f32x2 p0 = __builtin_amdgcn_cvt_pk_f32_fp8((int)uA.x, false);
      f32x2 p1 = __builtin_amdgcn_cvt_pk_f32_fp8((int)uA.x, true);
      f32x2 p2 = __builtin_amdgcn_cvt_pk_f32_fp8((int)uA.y, false);
      f32x2 p3 = __builtin_amdgcn_cvt_pk_f32_fp8((int)uA.y, true);
      f32x2 p4 = __builtin_amdgcn_cvt_pk_f32_fp8((int)uA.z, false);
      f32x2 p5 = __builtin_amdgcn_cvt_pk_f32_fp8((int)uA.z, true);
      f32x2 p6 = __builtin_amdgcn_cvt_pk_f32_fp8((int)uA.w, false);
      f32x2 p7 = __builtin_amdgcn_cvt_pk_f32_fp8((int)uA.w, true);
      a[0]+=xA*p0.x; a[1]+=xA*p0.y; a[2]+=xA*p1.x; a[3]+=xA*p1.y;
      a[4]+=xA*p2.x; a[5]+=xA*p2.y; a[6]+=xA*p3.x; a[7]+=xA*p3.y;
      a[8]+=xA*p4.x; a[9]+=xA*p4.y; a[10]+=xA*p5.x; a[11]+=xA*p5.y;
      a[12]+=xA*p6.x; a[13]+=xA*p6.y; a[14]+=xA*p7.x; a[15]+=xA*p7.y;
    }
    // compute current B (weight 0 past the tail)
    float eB = fB + sdh;
    eB = (eB > 0.f) ? eB : 0.2f*eB;
    float xB = (j + 1 < dg) ? __expf(eB) : 0.f;
    denB += xB;
    {
      f32x2 p0 = __builtin_amdgcn_cvt_pk_f32_fp8((int)uB.x, false);
      f32x2 p1 = __builtin_amdgcn_cvt_pk_f32_fp8((int)uB.x, true);
      f32x2 p2 = __builtin_amdgcn_cvt_pk_f32_fp8((int)uB.y, false);
      f32x2 p3 = __builtin_amdgcn_cvt_pk_f32_fp8((int)uB.y, true);
      f32x2 p4 = __builtin_amdgcn_cvt_pk_f32_fp8((int)uB.z, false);
      f32x2 p5 = __builtin_amdgcn_cvt_pk_f32_fp8((int)uB.z, true);
      f32x2 p6 = __builtin_amdgcn_cvt_pk_f32_fp8((int)uB.w, false);
      f32x2 p7 = __builtin_amdgcn_cvt_pk_f32_fp8((int)uB.w, true);
      b[0]+=xB*p0.x; b[1]+=xB*p0.y; b[2]+=xB*p1.x; b[3]+=xB*p1.y;
      b[4]+=xB*p2.x; b[5]+=xB*p2.y; b[6]+=xB*p3.x; b[7]+=xB*p3.y;
      b[8]+=xB*p4.x; b[9]+=xB*p4.y; b[10]+=xB*p5.x; b[11]+=xB*p5.y;
      b[12]+=xB*p6.x; b[13]+=xB*p6.y; b[14]+=xB*p7.x; b[15]+=xB*p7.y;
    }
    uA = vA; uB = vB; fA = gA; fB = gB; nA1 = nA2; nB1 = nB2;
  }

  float inv = 1.f / (denA + denB);
  float y[16];
  float4 bi[4];
  #pragma unroll
  for (int m=0;m<4;++m) bi[m] = *(const float4*)(bias + c0 + m*4);
  #pragma unroll
  for (int k=0;k<16;++k){
    float bv = ((const float*)bi)[k];
    y[k] = fmaxf((a[k]+b[k])*inv + bv, 0.f);
  }
  // layernorm over 256 channels within the 16-lane group (xor-closed, offsets 1..8)
  float sum = 0.f;
  #pragma unroll
  for (int k=0;k<16;++k) sum += y[k];
  #pragma unroll
  for (int o=8;o>=1;o>>=1) sum += __shfl_xor(sum, o);
  float mu = sum * (1.f/256.f);
  float d[16], sq = 0.f;
  #pragma unroll
  for (int k=0;k<16;++k){ d[k] = y[k]-mu; sq += d[k]*d[k]; }
  #pragma unroll
  for (int o=8;o>=1;o>>=1) sq += __shfl_xor(sq, o);
  float rs = rsqrtf(sq*(1.f/256.f) + LN_EPSF);
  float4 gv[4], qv[4];
  #pragma unroll
  for (int m=0;m<4;++m){
    gv[m] = *(const float4*)(g + c0 + m*4);
    qv[m] = *(const float4*)(bb + c0 + m*4);
  }
  float o16[16];
  #pragma unroll
  for (int k=0;k<16;++k)
    o16[k] = d[k]*rs*((const float*)gv)[k] + ((const float*)qv)[k];

  if (hout8){
    uint4 w;
    u32 w0 = (u32)__builtin_amdgcn_cvt_pk_fp8_f32(o16[0], o16[1], 0, false);
    w.x = (u32)__builtin_amdgcn_cvt_pk_fp8_f32(o16[2], o16[3], (int)w0, true);
    w0 = (u32)__builtin_amdgcn_cvt_pk_fp8_f32(o16[4], o16[5], 0, false);
    w.y = (u32)__builtin_amdgcn_cvt_pk_fp8_f32(o16[6], o16[7], (int)w0, true);
    w0 = (u32)__builtin_amdgcn_cvt_pk_fp8_f32(o16[8], o16[9], 0, false);
    w.z = (u32)__builtin_amdgcn_cvt_pk_fp8_f32(o16[10], o16[11], (int)w0, true);
    w0 = (u32)__builtin_amdgcn_cvt_pk_fp8_f32(o16[12], o16[13], 0, false);
    w.w = (u32)__builtin_amdgcn_cvt_pk_fp8_f32(o16[14], o16[15], (int)w0, true);
    *(uint4*)(hout8 + (size_t)n*HIDD + c0) = w;
  } else {
    uint4 o4a, o4b;
    o4a.x = pack2(o16[0], o16[1]);  o4a.y = pack2(o16[2], o16[3]);
    o4a.z = pack2(o16[4], o16[5]);  o4a.w = pack2(o16[6], o16[7]);
    o4b.x = pack2(o16[8], o16[9]);  o4b.y = pack2(o16[10], o16[11]);
    o4b.z = pack2(o16[12], o16[13]); o4b.w = pack2(o16[14], o16[15]);
    *(uint4*)(hout + (size_t)n*HIDD + c0) = o4a;
    *(uint4*)(hout + (size_t)n*HIDD + c0 + 8) = o4b;
  }
}

// ---------------- global mean pool (fp8 input): 1000 blocks, run-length atomics ----------------
__global__ __launch_bounds__(256) void k_pool(
    const u8* __restrict__ h8, const int* __restrict__ batch,
    float* __restrict__ pooled, float* __restrict__ cnt)
{
  const int chunk = 50;  // 1000*50 >= NN
  int t = threadIdx.x;
  int n0 = blockIdx.x*chunk;
  int n1 = min(n0 + chunk, NN);
  if (n0 >= n1) return;
  float acc = 0.f;
  int curb = batch[n0];
  int runStart = n0;
  bool hi = (t & 2) != 0;
  for (int n=n0; n<n1; ++n){
    int b = batch[n];
    if (b != curb){
      atomicAdd(&pooled[curb*HIDD + t], acc);
      if (t == 0) atomicAdd(&cnt[curb], (float)(n - runStart));
      acc = 0.f; curb = b; runStart = n;
    }
    u32 w = *(const u32*)(h8 + (size_t)n*HIDD + (t & ~3));
    f32x2 p = hi ? __builtin_amdgcn_cvt_pk_f32_fp8((int)w, true)
                 : __builtin_amdgcn_cvt_pk_f32_fp8((int)w, false);  // word-sel must be const
    acc += (t & 1) ? p.y : p.x;
  }
  atomicAdd(&pooled[curb*HIDD + t], acc);
  if (t == 0) atomicAdd(&cnt[curb], (float)(n1 - runStart));
}

// ---------------- readout: gelu(pooled@W1+b1)@W2+b2 (fp32, tiny) ----------------
__global__ __launch_bounds__(256) void k_readout(
    const float* __restrict__ pooled, const float* __restrict__ cnt,
    const float* __restrict__ w1, const float* __restrict__ b1,
    const float* __restrict__ w2, const float* __restrict__ b2,
    float* __restrict__ out)
{
  __shared__ float p[256], mid[256];
  int b = blockIdx.x, t = threadIdx.x;
  float c = fmaxf(cnt[b], 1.f);
  p[t] = pooled[b*HIDD + t] / c;
  __syncthreads();
  float acc = b1[t];
  for (int k=0;k<256;++k) acc += p[k]*w1[k*256+t];
  mid[t] = 0.5f*acc*(1.f + erff(acc*0.70710678118654752f));
  __syncthreads();
  float acc2 = b2[t];
  for (int k=0;k<256;++k) acc2 += mid[k]*w2[k*256+t];
  out[b*HIDD + t] = acc2;
}

extern "C" void kernel_launch(void* const* d_in, const int* in_sizes, int n_in,
                              void* d_out, int out_size, void* d_ws, size_t ws_size,
                              hipStream_t stream)
{
  const float* x    = (const float*)d_in[0];
  const float* remb = (const float*)d_in[1];
  const float* ipw  = (const float*)d_in[2];
  const float* ipb  = (const float*)d_in[3];
  const float* gatw = (const float*)d_in[4];
  const float* asrc = (const float*)d_in[5];
  const float* adst = (const float*)d_in[6];
  const float* gatb = (const float*)d_in[7];
  const float* lng  = (const float*)d_in[8];
  const float* lnb  = (const float*)d_in[9];
  const float* row1 = (const float*)d_in[10];
  const float* rob1 = (const float*)d_in[11];
  const float* row2 = (const float*)d_in[12];
  const float* rob2 = (const float*)d_in[13];
  const int* ei   = (const int*)d_in[14];
  const int* batch= (const int*)d_in[15];
  const int* rid  = (const int*)d_in[16];

  char* ws = (char*)d_ws;
  int*   deg  = (int*)  (ws + 0);          // 200192
  int*   cur  = (int*)  (ws + 200192);     // 200192
  float* cnt  = (float*)(ws + 400384);     // 256
  float* pool = (float*)(ws + 400640);     // 16384
  // ZERO_BYTES = 417024
  int*   row  = (int*)  (ws + 417024);     // 200192
  int*   part = (int*)  (ws + 617216);     // 1024
  int*   csr  = (int*)  (ws + 618240);     // 1800192 -> 2418432
  float* ss   = (float*)(ws + 2418432);    // 800768
  float* sd   = (float*)(ws + 3219200);    // 800768  -> 4019968
  u16*   vmat = (u16*)  (ws + 4019968);    // 32768   -> 4052736
  u16*   feats= (u16*)  (ws + 4052736);    // 19218432-> 23271168
  u16*   wtin = (u16*)  (ws + 23271168);   // 98304   -> 23369472  (fused (Win@W0)^T)
  u16*   wtl  = (u16*)  (ws + 23369472);   // 524288  -> 23893760
  u16*   hA   = (u16*)  (ws + 23893760);   // 25624576-> 49518336  (bf16 h / fp8 final)
  u8*    hA8  = (u8*)   (ws + 23893760);   // alias: final-layer fp8 h
  u8*    hB8  = (u8*)   (ws + 49518336);   // 12812288-> 62330624
  u16*   vmatc= (u16*)  (ws + 62330624);   // 6144    -> 62336768  (fused layer-0 scores)
  float* bias0= (float*)(ws + 62336768);   // 1056    -> 62337824  ([0,256)=bias, [256,264)=score consts)

  (void)hipMemsetAsync(ws, 0, 417024, stream);

  k_setup <<<7739, 256, 0, stream>>>(x, remb, rid, feats, ipw, gatw, wtin, wtl,
                                     asrc, adst, vmat, ei, deg, ipb, vmatc, bias0);
  k_scan1 <<<196, 256, 0, stream>>>(deg, row, part);
  k_scan23<<<196, 256, 0, stream>>>(row, part, 196);
  k_scatter<<<1758, 256, 0, stream>>>(ei, row, cur, csr);

  // layer 0 (fused inproj): feats@(Win@W0) + b_in@W0 -> hB8 + scores
  k_gemm<KIN><<<782, 256, 0, stream>>>(feats, wtin, bias0, vmatc, bias0 + 256,
                                       ss, sd, nullptr, hB8, NN);
  k_aggregate<<<3125, 256, 0, stream>>>(hB8, ss, sd, row, deg, csr,
                                        gatb + 0*HIDD, lng + 0*HIDD, lnb + 0*HIDD,
                                        hA, nullptr);

  for (int l = 1; l < 4; ++l){
    k_gemm<HIDD><<<782, 256, 0, stream>>>(hA, wtl + (size_t)l*HIDD*HIDD, nullptr,
                                          vmat + (size_t)l*16*256, nullptr,
                                          ss, sd, nullptr, hB8, NN);
    if (l < 3){
      k_aggregate<<<3125, 256, 0, stream>>>(hB8, ss, sd, row, deg, csr,
                                            gatb + l*HIDD, lng + l*HIDD, lnb + l*HIDD,
                                            hA, nullptr);
    } else {
      // final layer: write fp8 (pool decodes) — halves pool read + agg write traffic
      k_aggregate<<<3125, 256, 0, stream>>>(hB8, ss, sd, row, deg, csr,
                                            gatb + l*HIDD, lng + l*HIDD, lnb + l*HIDD,
                                            nullptr, hA8);
    }
  }

  k_pool   <<<1000, 256, 0, stream>>>(hA8, batch, pool, cnt);
  k_readout<<<16, 256, 0, stream>>>(pool, cnt, row1, rob1, row2, rob2, (float*)d_out);
}